// Round 1
// baseline (404.635 us; speedup 1.0000x reference)
//
#include <hip/hip_runtime.h>

// Two-compartment PK recurrence, reformulated as an affine scan.
// Per element t:  C <- C*g1 + h1,  D <- D*g2 + h2,  A = C*c3 + D*c4
//   g  = exp(lam*td)
//   h  = c * (exp(lam*td) - exp(lam*(td-d)))   [exactly 0 when d==0]
// Affine maps compose associatively -> block-level parallel scan over T.

constexpr int T_LEN  = 8192;
constexpr int BLOCK  = 1024;
constexpr int K      = T_LEN / BLOCK;   // 8 elements per thread
constexpr int NWAVES = BLOCK / 64;      // 16

__global__ __launch_bounds__(BLOCK) void vtdm_scan_kernel(
    const float* __restrict__ dose,
    const float* __restrict__ tdiff,
    const float* __restrict__ ccl,
    const float* __restrict__ eta1p,
    const float* __restrict__ eta2p,
    const float* __restrict__ eta3p,
    float* __restrict__ out)
{
    const int row  = blockIdx.x;
    const int tid  = threadIdx.x;
    const int lane = tid & 63;
    const int wid  = tid >> 6;

    // ---- scalar PK constants (wave-uniform) ----
    const float eta1 = eta1p[0], eta2 = eta2p[0], eta3 = eta3p[0];
    const float V1    = 33.1f * __expf(eta1);
    const float Q     = 6.99f * __expf(eta3);
    const float k12   = Q / V1;
    const float k21   = Q / 48.3f;
    const float R     = 1000.0f / V1;
    const float k10s  = 0.0396f * __expf(eta2) / V1;   // k10 = ccl * k10s
    const float sum12 = k12 + k21;
    const float RQ    = (R * k12) / k21;               // for c1/c2 via lam1*lam2 = k10*k21
    const float invk12 = 1.0f / k12;
    const float fourk21 = 4.0f * k21;

    const size_t base = (size_t)row * (size_t)T_LEN + (size_t)tid * (size_t)K;

    const float4 dv0 = *reinterpret_cast<const float4*>(dose  + base);
    const float4 dv1 = *reinterpret_cast<const float4*>(dose  + base + 4);
    const float4 tv0 = *reinterpret_cast<const float4*>(tdiff + base);
    const float4 tv1 = *reinterpret_cast<const float4*>(tdiff + base + 4);
    const float4 cv0 = *reinterpret_cast<const float4*>(ccl   + base);
    const float4 cv1 = *reinterpret_cast<const float4*>(ccl   + base + 4);

    const float dd[K]  = {dv0.x, dv0.y, dv0.z, dv0.w, dv1.x, dv1.y, dv1.z, dv1.w};
    const float tdv[K] = {tv0.x, tv0.y, tv0.z, tv0.w, tv1.x, tv1.y, tv1.z, tv1.w};
    const float ccv[K] = {cv0.x, cv0.y, cv0.z, cv0.w, cv1.x, cv1.y, cv1.z, cv1.w};

    float g1[K], h1[K], g2[K], h2[K], c3a[K], c4a[K];

    #pragma unroll
    for (int i = 0; i < K; ++i) {
        const float k10   = ccv[i] * k10s;
        const float s     = k10 + sum12;
        const float disc  = s * s - fourk21 * k10;
        const float delta = sqrtf(disc);
        const float lam1  = -0.5f * (s + delta);
        const float lam2  =  0.5f * (delta - s);
        // c1 = -R*k12/(lam1*delta) = -(R*k12/k21)*lam2/(k10*delta)   [lam1*lam2 = k10*k21]
        // c2 =  R*k12/(lam2*delta) =  (R*k12/k21)*lam1/(k10*delta)
        const float inv   = __fdividef(1.0f, k10 * delta);
        const float c1    = -RQ * lam2 * inv;
        const float c2    =  RQ * lam1 * inv;
        c3a[i] = (lam1 + k21) * invk12;
        c4a[i] = (lam2 + k21) * invk12;

        const float td  = tdv[i];
        const float tmd = td - dd[i];          // == td bit-exactly when dose==0
        const float e1  = __expf(lam1 * td);
        const float f1  = __expf(lam1 * tmd);
        const float e2  = __expf(lam2 * td);
        const float f2  = __expf(lam2 * tmd);
        g1[i] = e1;  h1[i] = c1 * (e1 - f1);   // h == 0 exactly when dose==0
        g2[i] = e2;  h2[i] = c2 * (e2 - f2);
    }

    // ---- thread-local affine composition over the K elements ----
    float G1 = g1[0], H1 = h1[0], G2 = g2[0], H2 = h2[0];
    #pragma unroll
    for (int i = 1; i < K; ++i) {
        H1 = g1[i] * H1 + h1[i];   G1 = g1[i] * G1;
        H2 = g2[i] * H2 + h2[i];   G2 = g2[i] * G2;
    }

    // ---- wave-level inclusive scan of affine maps (compose(prev, cur)) ----
    #pragma unroll
    for (int off = 1; off < 64; off <<= 1) {
        const float pg1 = __shfl_up(G1, off, 64);
        const float ph1 = __shfl_up(H1, off, 64);
        const float pg2 = __shfl_up(G2, off, 64);
        const float ph2 = __shfl_up(H2, off, 64);
        if (lane >= off) {
            H1 = G1 * ph1 + H1;  G1 = G1 * pg1;
            H2 = G2 * ph2 + H2;  G2 = G2 * pg2;
        }
    }

    // ---- block level: wave totals -> LDS, exclusive wave prefix ----
    __shared__ float sG1[NWAVES], sH1[NWAVES], sG2[NWAVES], sH2[NWAVES];
    if (lane == 63) {
        sG1[wid] = G1;  sH1[wid] = H1;
        sG2[wid] = G2;  sH2[wid] = H2;
    }
    __syncthreads();

    // Row-initial state is (0,0), so the state entering this wave is just the
    // H-component of the composed exclusive wave prefix.
    float WH1 = 0.0f, WH2 = 0.0f;
    for (int w = 0; w < wid; ++w) {
        WH1 = sG1[w] * WH1 + sH1[w];
        WH2 = sG2[w] * WH2 + sH2[w];
    }

    // ---- lane-exclusive map within the wave ----
    float LG1 = __shfl_up(G1, 1, 64);
    float LH1 = __shfl_up(H1, 1, 64);
    float LG2 = __shfl_up(G2, 1, 64);
    float LH2 = __shfl_up(H2, 1, 64);
    if (lane == 0) { LG1 = 1.0f; LH1 = 0.0f; LG2 = 1.0f; LH2 = 0.0f; }

    float C = LG1 * WH1 + LH1;   // state entering this thread
    float D = LG2 * WH2 + LH2;

    // ---- replay the K elements with the carry; emit A ----
    float a[K];
    #pragma unroll
    for (int i = 0; i < K; ++i) {
        C = C * g1[i] + h1[i];
        D = D * g2[i] + h2[i];
        a[i] = C * c3a[i] + D * c4a[i];
    }

    *reinterpret_cast<float4*>(out + base)     = make_float4(a[0], a[1], a[2], a[3]);
    *reinterpret_cast<float4*>(out + base + 4) = make_float4(a[4], a[5], a[6], a[7]);
}

extern "C" void kernel_launch(void* const* d_in, const int* in_sizes, int n_in,
                              void* d_out, int out_size, void* d_ws, size_t ws_size,
                              hipStream_t stream) {
    const float* dose  = (const float*)d_in[0];
    const float* tdiff = (const float*)d_in[1];
    const float* ccl   = (const float*)d_in[2];
    const float* eta1  = (const float*)d_in[3];
    const float* eta2  = (const float*)d_in[4];
    const float* eta3  = (const float*)d_in[5];
    float* outp = (float*)d_out;

    const int B = in_sizes[0] / T_LEN;
    vtdm_scan_kernel<<<dim3(B), dim3(BLOCK), 0, stream>>>(
        dose, tdiff, ccl, eta1, eta2, eta3, outp);
}

// Round 2
// 401.242 us; speedup vs baseline: 1.0085x; 1.0085x over previous
//
#include <hip/hip_runtime.h>

// Two-compartment PK recurrence as an affine scan, packed-FP32 edition.
// Per element t:  (C,D) <- (C,D)*g + h   (pairwise, v_pk ops),  A = C*c3 + D*c4
//   g = exp2(lamL*td),  h = c12*(exp2(lamL*td) - exp2(lamL*(td-d)))  [==0 when d==0]

typedef float f2 __attribute__((ext_vector_type(2)));

constexpr int T_LEN  = 8192;
constexpr int BLOCK  = 1024;
constexpr int K      = T_LEN / BLOCK;   // 8
constexpr int NWAVES = BLOCK / 64;      // 16

__device__ __forceinline__ f2 sp(float x) { f2 r; r.x = x; r.y = x; return r; }
__device__ __forceinline__ f2 vfma(f2 a, f2 b, f2 c) { return __builtin_elementwise_fma(a, b, c); }

__global__ __launch_bounds__(BLOCK) void vtdm_scan_kernel(
    const float* __restrict__ dose,
    const float* __restrict__ tdiff,
    const float* __restrict__ ccl,
    const float* __restrict__ eta1p,
    const float* __restrict__ eta2p,
    const float* __restrict__ eta3p,
    float* __restrict__ out)
{
    const int row  = blockIdx.x;
    const int tid  = threadIdx.x;
    const int lane = tid & 63;
    const int wid  = tid >> 6;

    const size_t base = (size_t)row * (size_t)T_LEN + (size_t)tid * (size_t)K;

    // issue the 6 vector loads first; scalar math overlaps the latency
    const float4 dv0 = *reinterpret_cast<const float4*>(dose  + base);
    const float4 dv1 = *reinterpret_cast<const float4*>(dose  + base + 4);
    const float4 tv0 = *reinterpret_cast<const float4*>(tdiff + base);
    const float4 tv1 = *reinterpret_cast<const float4*>(tdiff + base + 4);
    const float4 cv0 = *reinterpret_cast<const float4*>(ccl   + base);
    const float4 cv1 = *reinterpret_cast<const float4*>(ccl   + base + 4);

    // ---- scalar PK constants (wave-uniform) ----
    const float eta1 = eta1p[0], eta2 = eta2p[0], eta3 = eta3p[0];
    const float V1      = 33.1f * __expf(eta1);
    const float Q       = 6.99f * __expf(eta3);
    const float k12     = Q / V1;
    const float k21     = Q / 48.3f;
    const float R       = 1000.0f / V1;
    const float k10s    = 0.0396f * __expf(eta2) / V1;   // k10 = ccl * k10s
    const float sum12   = k12 + k21;
    const float RQ      = (R * k12) / k21;               // lam1*lam2 = k10*k21
    const float invk12  = 1.0f / k12;
    const float k21ik12 = k21 * invk12;
    const float fourk21 = 4.0f * k21;
    const float LOG2E   = 1.4426950408889634f;
    f2 halfpm; halfpm.x = -0.5f; halfpm.y = 0.5f;        // (-, +) for (lam1, lam2)
    f2 RQpm;   RQpm.x   = -RQ;   RQpm.y   = RQ;

    const float dd[K]  = {dv0.x, dv0.y, dv0.z, dv0.w, dv1.x, dv1.y, dv1.z, dv1.w};
    const float tdv[K] = {tv0.x, tv0.y, tv0.z, tv0.w, tv1.x, tv1.y, tv1.z, tv1.w};
    const float ccv[K] = {cv0.x, cv0.y, cv0.z, cv0.w, cv1.x, cv1.y, cv1.z, cv1.w};

    f2 g[K], h[K], c34[K];

    #pragma unroll
    for (int i = 0; i < K; ++i) {
        const float k10   = ccv[i] * k10s;
        const float s     = k10 + sum12;
        const float m     = fourk21 * k10;
        const float disc  = fmaf(s, s, -m);
        const float delta = __builtin_amdgcn_sqrtf(disc);
        const float t     = -0.5f * s;
        f2 lam = vfma(halfpm, sp(delta), sp(t));         // (lam1, lam2)
        const float inv   = __builtin_amdgcn_rcpf(k10 * delta);
        f2 lamsw; lamsw.x = lam.y; lamsw.y = lam.x;      // op_sel-foldable swap
        f2 c12 = (RQpm * lamsw) * sp(inv);               // (c1, c2)
        c34[i] = vfma(lam, sp(invk12), sp(k21ik12));     // ((lam+k21)/k12)

        const float td  = tdv[i];
        const float tmd = td - dd[i];                    // == td bit-exact when d==0
        f2 lamL = lam * sp(LOG2E);
        f2 ae = lamL * sp(td);
        f2 af = lamL * sp(tmd);
        f2 e, f;
        e.x = exp2f(ae.x);  e.y = exp2f(ae.y);
        f.x = exp2f(af.x);  f.y = exp2f(af.y);
        g[i] = e;
        h[i] = c12 * (e - f);                            // exactly 0 when d==0
    }

    // ---- thread-local affine composition over the K elements ----
    f2 G = g[0], H = h[0];
    #pragma unroll
    for (int i = 1; i < K; ++i) {
        H = vfma(g[i], H, h[i]);
        G = g[i] * G;
    }

    // ---- wave-level inclusive Kogge-Stone scan of affine maps ----
    #pragma unroll
    for (int off = 1; off < 64; off <<= 1) {
        f2 pg, ph;
        pg.x = __shfl_up(G.x, off, 64);  pg.y = __shfl_up(G.y, off, 64);
        ph.x = __shfl_up(H.x, off, 64);  ph.y = __shfl_up(H.y, off, 64);
        if (lane < off) { pg = sp(1.0f); ph = sp(0.0f); }
        H = vfma(G, ph, H);
        G = G * pg;
    }

    // ---- block level: wave totals -> LDS, exclusive wave-state prefix ----
    __shared__ f2 sG[NWAVES], sH[NWAVES];
    if (lane == 63) { sG[wid] = G; sH[wid] = H; }
    __syncthreads();

    // Row-initial state is (0,0): state entering this wave = composed H of prior waves.
    f2 W = sp(0.0f);
    for (int w = 0; w < wid; ++w) W = vfma(sG[w], W, sH[w]);

    // ---- lane-exclusive map within the wave ----
    f2 LG, LH;
    LG.x = __shfl_up(G.x, 1, 64);  LG.y = __shfl_up(G.y, 1, 64);
    LH.x = __shfl_up(H.x, 1, 64);  LH.y = __shfl_up(H.y, 1, 64);
    if (lane == 0) { LG = sp(1.0f); LH = sp(0.0f); }

    f2 CD = vfma(LG, W, LH);   // (C, D) entering this thread

    // ---- replay the K elements with the carry; emit A ----
    float a[K];
    #pragma unroll
    for (int i = 0; i < K; ++i) {
        CD = vfma(g[i], CD, h[i]);
        a[i] = fmaf(CD.y, c34[i].y, CD.x * c34[i].x);
    }

    *reinterpret_cast<float4*>(out + base)     = make_float4(a[0], a[1], a[2], a[3]);
    *reinterpret_cast<float4*>(out + base + 4) = make_float4(a[4], a[5], a[6], a[7]);
}

extern "C" void kernel_launch(void* const* d_in, const int* in_sizes, int n_in,
                              void* d_out, int out_size, void* d_ws, size_t ws_size,
                              hipStream_t stream) {
    const float* dose  = (const float*)d_in[0];
    const float* tdiff = (const float*)d_in[1];
    const float* ccl   = (const float*)d_in[2];
    const float* eta1  = (const float*)d_in[3];
    const float* eta2  = (const float*)d_in[4];
    const float* eta3  = (const float*)d_in[5];
    float* outp = (float*)d_out;

    const int B = in_sizes[0] / T_LEN;
    vtdm_scan_kernel<<<dim3(B), dim3(BLOCK), 0, stream>>>(
        dose, tdiff, ccl, eta1, eta2, eta3, outp);
}